// Round 4
// baseline (3989.647 us; speedup 1.0000x reference)
//
#include <hip/hip_runtime.h>

#define D_ 512
#define ND_ 2048   // 4*D
#define KS_ 24
#define TB_ 32
#define B_ 8192

typedef __attribute__((ext_vector_type(8))) short short8;
typedef __attribute__((ext_vector_type(16))) float f32x16;
typedef unsigned short u16;

// byte offset into swizzled h tile: row in [0,32), kb = byte offset along d (d*2)
#define SWZ(row, kb) (((row) * 1024) + ((kb) ^ (((row) & 15) << 4)))

__device__ __forceinline__ u16 f2bf(float f) {
  union { float f; unsigned int u; } v; v.f = f;
  unsigned int u = v.u;
  return (u16)((u + 0x7FFFu + ((u >> 16) & 1u)) >> 16);
}

__device__ __forceinline__ float sigm(float x) { return 1.0f / (1.0f + __expf(-x)); }
__device__ __forceinline__ float tanh_(float x) {
  float e = __expf(2.0f * x);
  return (e - 1.0f) / (e + 1.0f);
}

// Pack Wu (512 x 2048 f32, row-major) into MFMA B-fragment order, bf16.
// Block (nt, ks): nt in [0,64) over 32-wide n-tiles, ks in [0,32) over K=16 slices.
// Within block: lane l, elem j  <->  B[k = ks*16 + 8*(l>>5) + j][n = nt*32 + (l&31)]
// Block storage: 64 lanes * 16B contiguous (1KB), block offset = (nt*32+ks)*1KB.
__global__ __launch_bounds__(256) void pack_wu_kernel(const float* __restrict__ Wu,
                                                      u16* __restrict__ pk) {
  int idx = blockIdx.x * 256 + threadIdx.x;  // 131072 total
  int lane = idx & 63;
  int blk  = idx >> 6;        // nt*32 + ks
  int ks   = blk & 31;
  int nt   = blk >> 5;
  int col  = nt * 32 + (lane & 31);
  int k0   = ks * 16 + (lane >> 5) * 8;
  u16 t[8];
#pragma unroll
  for (int j = 0; j < 8; ++j) t[j] = f2bf(Wu[(size_t)(k0 + j) * ND_ + col]);
  int4 w;
  w.x = t[0] | (t[1] << 16); w.y = t[2] | (t[3] << 16);
  w.z = t[4] | (t[5] << 16); w.w = t[6] | (t[7] << 16);
  *reinterpret_cast<int4*>(pk + (size_t)blk * 512 + lane * 8) = w;
}

// 256 blocks x 512 threads (8 waves, 2 waves/SIMD -> 256-VGPR budget).
// Wave wv owns 2 n-tiles (d-cols [wv*64, wv*64+64)) of each gate; block = 32 rows.
// Inner loop: explicit 2-deep register ping-pong keeps 8 global loads in flight
// per wave (64 KB/CU outstanding) to saturate the L2->CU path on the 2 MB/step
// Wu stream. c in LDS, h double-buffered in LDS.
__global__ __launch_bounds__(512, 2) void lstm_kernel(
    const float* __restrict__ initial, const float* __restrict__ enc_h,
    const float* __restrict__ enc_c, const float* __restrict__ Wx,
    const float* __restrict__ bias, const float* __restrict__ w1,
    const float* __restrict__ b1, const float* __restrict__ w2,
    const float* __restrict__ b2, const u16* __restrict__ wu,
    float* __restrict__ out) {
  __shared__ __align__(16) unsigned char hbuf[2][TB_ * 1024];  // swizzled bf16 h, dbuf
  __shared__ float c_lds[TB_][D_];                             // 64 KB f32 cell state
  __shared__ float x_lds[TB_];
  __shared__ float ly1[8][TB_];
  __shared__ float ly2[8][TB_];

  const int tid = threadIdx.x;
  const int wv  = tid >> 6;    // 0..7
  const int l   = tid & 63;
  const int l31 = l & 31;
  const int lhi = l >> 5;
  const int b0  = blockIdx.x * TB_;

  // ---- stage initial h (bf16, swizzled) + c (f32) into LDS: 512 threads ----
  {
    int row = tid >> 4;   // 0..31
    int seg = tid & 15;   // 32 cols each
    const float* src = enc_h + (size_t)(b0 + row) * D_ + seg * 32;
#pragma unroll
    for (int jb = 0; jb < 4; ++jb) {
      u16 t[8];
#pragma unroll
      for (int j = 0; j < 8; ++j) t[j] = f2bf(src[jb * 8 + j]);
      int kb = seg * 64 + jb * 16;
      int4 w;
      w.x = t[0] | (t[1] << 16); w.y = t[2] | (t[3] << 16);
      w.z = t[4] | (t[5] << 16); w.w = t[6] | (t[7] << 16);
      *reinterpret_cast<int4*>(&hbuf[0][SWZ(row, kb)]) = w;
    }
    const float* csrc = enc_c + (size_t)(b0 + row) * D_ + seg * 32;
    float* cdst = &c_lds[row][seg * 32];
#pragma unroll
    for (int j = 0; j < 32; j += 4)
      *reinterpret_cast<float4*>(cdst + j) = *reinterpret_cast<const float4*>(csrc + j);
  }
  if (tid < TB_) x_lds[tid] = initial[b0 + tid];

  // ---- per-lane step-invariant values (2 col sets) ----
  const int c0 = wv * 64 + l31;
  const int c1 = c0 + 32;
  float wx0[4], wx1[4], bb0[4], bb1[4];
#pragma unroll
  for (int g = 0; g < 4; ++g) {
    wx0[g] = Wx[g * D_ + c0];  wx1[g] = Wx[g * D_ + c1];
    bb0[g] = bias[g * D_ + c0]; bb1[g] = bias[g * D_ + c1];
  }
  const float w1v0 = w1[c0], w1v1 = w1[c1];
  const float w2v0 = w2[c0], w2v1 = w2[c1];
  const float b1v = b1[0], b2v = b2[0];

  // base pointers for the 8 fragment streams (gate g, tile t = 2*wv+t)
  const u16* wub[8];
#pragma unroll
  for (int g = 0; g < 4; ++g)
#pragma unroll
    for (int t = 0; t < 2; ++t)
      wub[g * 2 + t] = wu + (size_t)((g * 16 + wv * 2 + t) * 32) * 512 + (size_t)l * 8;

  __syncthreads();

  for (int s = 0; s < KS_; ++s) {
    const unsigned char* hr = hbuf[s & 1];
    unsigned char* hw = hbuf[(s & 1) ^ 1];

    f32x16 acc[2][4];
#pragma unroll
    for (int t = 0; t < 2; ++t)
#pragma unroll
      for (int g = 0; g < 4; ++g) acc[t][g] = (f32x16){};

    short8 fA[8], fB[8];
#pragma unroll
    for (int f = 0; f < 8; ++f)
      fA[f] = *reinterpret_cast<const short8*>(wub[f]);

    for (int ks = 0; ks < 32; ks += 2) {
      const int ks1 = ks + 1;
      const int ks2 = (ks + 2) & 31;  // wrap keeps last prefetch in-bounds (unused)
#pragma unroll
      for (int f = 0; f < 8; ++f)
        fB[f] = *reinterpret_cast<const short8*>(wub[f] + (size_t)ks1 * 512);
      short8 a0 = *reinterpret_cast<const short8*>(&hr[SWZ(l31, ks * 32 + lhi * 16)]);
#pragma unroll
      for (int g = 0; g < 4; ++g)
#pragma unroll
        for (int t = 0; t < 2; ++t)
          acc[t][g] = __builtin_amdgcn_mfma_f32_32x32x16_bf16(a0, fA[g * 2 + t], acc[t][g], 0, 0, 0);
#pragma unroll
      for (int f = 0; f < 8; ++f)
        fA[f] = *reinterpret_cast<const short8*>(wub[f] + (size_t)ks2 * 512);
      short8 a1 = *reinterpret_cast<const short8*>(&hr[SWZ(l31, ks1 * 32 + lhi * 16)]);
#pragma unroll
      for (int g = 0; g < 4; ++g)
#pragma unroll
        for (int t = 0; t < 2; ++t)
          acc[t][g] = __builtin_amdgcn_mfma_f32_32x32x16_bf16(a1, fB[g * 2 + t], acc[t][g], 0, 0, 0);
    }

    float y1p[16], y2p[16];
#pragma unroll
    for (int r = 0; r < 16; ++r) {
      const int row = (r & 3) + 8 * (r >> 2) + 4 * lhi;
      float xv = x_lds[row];
      // tile 0
      float zi = acc[0][0][r] + xv * wx0[0] + bb0[0];
      float zf = acc[0][1][r] + xv * wx0[1] + bb0[1];
      float zg = acc[0][2][r] + xv * wx0[2] + bb0[2];
      float zo = acc[0][3][r] + xv * wx0[3] + bb0[3];
      float cn0 = sigm(zf) * c_lds[row][c0] + sigm(zi) * tanh_(zg);
      c_lds[row][c0] = cn0;
      float h0 = sigm(zo) * tanh_(cn0);
      *reinterpret_cast<u16*>(&hw[SWZ(row, c0 * 2)]) = f2bf(h0);
      // tile 1
      float zi1 = acc[1][0][r] + xv * wx1[0] + bb1[0];
      float zf1 = acc[1][1][r] + xv * wx1[1] + bb1[1];
      float zg1 = acc[1][2][r] + xv * wx1[2] + bb1[2];
      float zo1 = acc[1][3][r] + xv * wx1[3] + bb1[3];
      float cn1 = sigm(zf1) * c_lds[row][c1] + sigm(zi1) * tanh_(zg1);
      c_lds[row][c1] = cn1;
      float h1 = sigm(zo1) * tanh_(cn1);
      *reinterpret_cast<u16*>(&hw[SWZ(row, c1 * 2)]) = f2bf(h1);
      y1p[r] = h0 * w1v0 + h1 * w1v1;
      y2p[r] = h0 * w2v0 + h1 * w2v1;
    }

    // reduce y partials across the 32 lanes of each half-wave
#pragma unroll
    for (int m = 1; m < 32; m <<= 1) {
#pragma unroll
      for (int r = 0; r < 16; ++r) {
        y1p[r] += __shfl_xor(y1p[r], m);
        y2p[r] += __shfl_xor(y2p[r], m);
      }
    }
    if (l31 == 0) {
#pragma unroll
      for (int r = 0; r < 16; ++r) {
        const int row = (r & 3) + 8 * (r >> 2) + 4 * lhi;
        ly1[wv][row] = y1p[r];
        ly2[wv][row] = y2p[r];
      }
    }
    __syncthreads();  // (1) new h, c, ly complete

    if (tid < TB_) {
      float s1 = b1v, s2 = b2v;
#pragma unroll
      for (int wq = 0; wq < 8; ++wq) { s1 += ly1[wq][tid]; s2 += ly2[wq][tid]; }
      float y1 = sigm(s1);
      float y2 = (s2 > 0.f) ? s2 : (__expf(s2) - 1.0f);
      out[(size_t)(b0 + tid) * KS_ + s] = y1;
      out[(size_t)B_ * KS_ + (size_t)(b0 + tid) * KS_ + s] = y2;
      x_lds[tid] = y1;
    }
    __syncthreads();  // (2) x visible before next step
  }
}

extern "C" void kernel_launch(void* const* d_in, const int* in_sizes, int n_in,
                              void* d_out, int out_size, void* d_ws, size_t ws_size,
                              hipStream_t stream) {
  const float* initial = (const float*)d_in[0];
  const float* enc_h   = (const float*)d_in[1];
  const float* enc_c   = (const float*)d_in[2];
  const float* Wx      = (const float*)d_in[3];
  const float* Wu      = (const float*)d_in[4];
  const float* bias    = (const float*)d_in[5];
  const float* w1      = (const float*)d_in[6];
  const float* b1      = (const float*)d_in[7];
  const float* w2      = (const float*)d_in[8];
  const float* b2      = (const float*)d_in[9];
  u16* pk = (u16*)d_ws;  // 2 MB packed Wu (bf16, MFMA B-frag order)

  pack_wu_kernel<<<512, 256, 0, stream>>>(Wu, pk);
  lstm_kernel<<<256, 512, 0, stream>>>(initial, enc_h, enc_c, Wx, bias, w1, b1,
                                       w2, b2, pk, (float*)d_out);
}

// Round 5
// 3143.909 us; speedup vs baseline: 1.2690x; 1.2690x over previous
//
#include <hip/hip_runtime.h>

#define D_ 512
#define ND_ 2048   // 4*D
#define KS_ 24
#define TB_ 32
#define B_ 8192

typedef __attribute__((ext_vector_type(8))) short short8;
typedef __attribute__((ext_vector_type(16))) float f32x16;
typedef unsigned short u16;

// byte offset into swizzled h tile: row in [0,32), kb = byte offset along d (d*2)
#define SWZ(row, kb) (((row) * 1024) + ((kb) ^ (((row) & 15) << 4)))

__device__ __forceinline__ u16 f2bf(float f) {
  union { float f; unsigned int u; } v; v.f = f;
  unsigned int u = v.u;
  return (u16)((u + 0x7FFFu + ((u >> 16) & 1u)) >> 16);
}

__device__ __forceinline__ float sigm(float x) { return 1.0f / (1.0f + __expf(-x)); }
__device__ __forceinline__ float tanh_(float x) {
  float e = __expf(2.0f * x);
  return (e - 1.0f) / (e + 1.0f);
}

// Pack Wu (512 x 2048 f32, row-major) into MFMA B-fragment order, bf16.
// Block (nt, ks): nt in [0,64) over 32-wide n-tiles, ks in [0,32) over K=16 slices.
// Within block: lane l, elem j  <->  B[k = ks*16 + 8*(l>>5) + j][n = nt*32 + (l&31)]
// Block storage: 64 lanes * 16B contiguous (1KB), block offset = (nt*32+ks)*1KB.
__global__ __launch_bounds__(256) void pack_wu_kernel(const float* __restrict__ Wu,
                                                      u16* __restrict__ pk) {
  int idx = blockIdx.x * 256 + threadIdx.x;  // 131072 total
  int lane = idx & 63;
  int blk  = idx >> 6;        // nt*32 + ks
  int ks   = blk & 31;
  int nt   = blk >> 5;
  int col  = nt * 32 + (lane & 31);
  int k0   = ks * 16 + (lane >> 5) * 8;
  u16 t[8];
#pragma unroll
  for (int j = 0; j < 8; ++j) t[j] = f2bf(Wu[(size_t)(k0 + j) * ND_ + col]);
  int4 w;
  w.x = t[0] | (t[1] << 16); w.y = t[2] | (t[3] << 16);
  w.z = t[4] | (t[5] << 16); w.w = t[6] | (t[7] << 16);
  *reinterpret_cast<int4*>(pk + (size_t)blk * 512 + lane * 8) = w;
}

// 256 blocks x 1024 threads (16 waves, 4 waves/SIMD -> 128 unified regs/wave).
// Wave wv owns 1 n-tile (32 d-cols) of each of the 4 gates; block = 32 rows.
// K-loop: explicit 2-deep ping-pong of the 4 B-fragment streams (32 VGPR)
// keeps ~4-8 KB of L2 loads in flight per wave (64-128 KB/CU) to cover L2
// latency on the 2 MB/step Wu stream. acc 64 AGPR; c in LDS; h dbuf in LDS.
__global__ __launch_bounds__(1024, 4) void lstm_kernel(
    const float* __restrict__ initial, const float* __restrict__ enc_h,
    const float* __restrict__ enc_c, const float* __restrict__ Wx,
    const float* __restrict__ bias, const float* __restrict__ w1,
    const float* __restrict__ b1, const float* __restrict__ w2,
    const float* __restrict__ b2, const u16* __restrict__ wu,
    float* __restrict__ out) {
  __shared__ __align__(16) unsigned char hbuf[2][TB_ * 1024];  // swizzled bf16 h, dbuf
  __shared__ float c_lds[TB_][D_];                             // 64 KB f32 cell state
  __shared__ float x_lds[TB_];
  __shared__ float ly1[16][TB_];
  __shared__ float ly2[16][TB_];

  const int tid = threadIdx.x;
  const int wv  = tid >> 6;    // 0..15  == n-tile index within each gate region
  const int l   = tid & 63;
  const int l31 = l & 31;
  const int lhi = l >> 5;
  const int b0  = blockIdx.x * TB_;

  // ---- stage initial h (bf16, swizzled) + c (f32) into LDS: 1024 threads ----
  {
    int row = tid >> 5;   // 0..31
    int seg = tid & 31;   // 16 cols each
    const float* src = enc_h + (size_t)(b0 + row) * D_ + seg * 16;
#pragma unroll
    for (int jb = 0; jb < 2; ++jb) {
      u16 t[8];
#pragma unroll
      for (int j = 0; j < 8; ++j) t[j] = f2bf(src[jb * 8 + j]);
      int kb = seg * 32 + jb * 16;
      int4 w;
      w.x = t[0] | (t[1] << 16); w.y = t[2] | (t[3] << 16);
      w.z = t[4] | (t[5] << 16); w.w = t[6] | (t[7] << 16);
      *reinterpret_cast<int4*>(&hbuf[0][SWZ(row, kb)]) = w;
    }
    const float* csrc = enc_c + (size_t)(b0 + row) * D_ + seg * 16;
    float* cdst = &c_lds[row][seg * 16];
#pragma unroll
    for (int j = 0; j < 16; j += 4)
      *reinterpret_cast<float4*>(cdst + j) = *reinterpret_cast<const float4*>(csrc + j);
  }
  if (tid < TB_) x_lds[tid] = initial[b0 + tid];

  // ---- per-lane step-invariant values ----
  const int col = wv * 32 + l31;     // d-column owned by this lane
  float wx[4], bb[4];
#pragma unroll
  for (int g = 0; g < 4; ++g) {
    wx[g] = Wx[g * D_ + col];
    bb[g] = bias[g * D_ + col];
  }
  const float w1v = w1[col], w2v = w2[col];
  const float b1v = b1[0], b2v = b2[0];

  // 4 B-fragment stream bases (gate g, n-tile = g*16 + wv)
  const u16* wub0 = wu + (size_t)(( 0 + wv) * 32) * 512 + (size_t)l * 8;
  const u16* wub1 = wu + (size_t)((16 + wv) * 32) * 512 + (size_t)l * 8;
  const u16* wub2 = wu + (size_t)((32 + wv) * 32) * 512 + (size_t)l * 8;
  const u16* wub3 = wu + (size_t)((48 + wv) * 32) * 512 + (size_t)l * 8;

  __syncthreads();

  const int abase = lhi * 16;

  for (int s = 0; s < KS_; ++s) {
    const unsigned char* hr = hbuf[s & 1];
    unsigned char* hw = hbuf[(s & 1) ^ 1];

    f32x16 acc0 = {}, acc1 = {}, acc2 = {}, acc3 = {};

    short8 fA0 = *reinterpret_cast<const short8*>(wub0);
    short8 fA1 = *reinterpret_cast<const short8*>(wub1);
    short8 fA2 = *reinterpret_cast<const short8*>(wub2);
    short8 fA3 = *reinterpret_cast<const short8*>(wub3);

    for (int ks = 0; ks < 32; ks += 2) {
      const size_t o1 = (size_t)(ks + 1) * 512;
      short8 fB0 = *reinterpret_cast<const short8*>(wub0 + o1);
      short8 fB1 = *reinterpret_cast<const short8*>(wub1 + o1);
      short8 fB2 = *reinterpret_cast<const short8*>(wub2 + o1);
      short8 fB3 = *reinterpret_cast<const short8*>(wub3 + o1);
      short8 a0 = *reinterpret_cast<const short8*>(&hr[SWZ(l31, ks * 32 + abase)]);
      acc0 = __builtin_amdgcn_mfma_f32_32x32x16_bf16(a0, fA0, acc0, 0, 0, 0);
      acc1 = __builtin_amdgcn_mfma_f32_32x32x16_bf16(a0, fA1, acc1, 0, 0, 0);
      acc2 = __builtin_amdgcn_mfma_f32_32x32x16_bf16(a0, fA2, acc2, 0, 0, 0);
      acc3 = __builtin_amdgcn_mfma_f32_32x32x16_bf16(a0, fA3, acc3, 0, 0, 0);
      const size_t o2 = (size_t)((ks + 2) & 31) * 512;  // wrap: last prefetch unused
      fA0 = *reinterpret_cast<const short8*>(wub0 + o2);
      fA1 = *reinterpret_cast<const short8*>(wub1 + o2);
      fA2 = *reinterpret_cast<const short8*>(wub2 + o2);
      fA3 = *reinterpret_cast<const short8*>(wub3 + o2);
      short8 a1 = *reinterpret_cast<const short8*>(&hr[SWZ(l31, (ks + 1) * 32 + abase)]);
      acc0 = __builtin_amdgcn_mfma_f32_32x32x16_bf16(a1, fB0, acc0, 0, 0, 0);
      acc1 = __builtin_amdgcn_mfma_f32_32x32x16_bf16(a1, fB1, acc1, 0, 0, 0);
      acc2 = __builtin_amdgcn_mfma_f32_32x32x16_bf16(a1, fB2, acc2, 0, 0, 0);
      acc3 = __builtin_amdgcn_mfma_f32_32x32x16_bf16(a1, fB3, acc3, 0, 0, 0);
    }

    float y1p[16], y2p[16];
#pragma unroll
    for (int r = 0; r < 16; ++r) {
      const int row = (r & 3) + 8 * (r >> 2) + 4 * lhi;
      float xv = x_lds[row];
      float zi = acc0[r] + xv * wx[0] + bb[0];
      float zf = acc1[r] + xv * wx[1] + bb[1];
      float zg = acc2[r] + xv * wx[2] + bb[2];
      float zo = acc3[r] + xv * wx[3] + bb[3];
      float ig = sigm(zi);
      float fg = sigm(zf);
      float gg = tanh_(zg);
      float og = sigm(zo);
      float cn = fg * c_lds[row][col] + ig * gg;
      c_lds[row][col] = cn;
      float hn = og * tanh_(cn);
      *reinterpret_cast<u16*>(&hw[SWZ(row, col * 2)]) = f2bf(hn);
      y1p[r] = hn * w1v;
      y2p[r] = hn * w2v;
    }

    // reduce y partials across the 32 d-columns held by this half-wave
#pragma unroll
    for (int m = 1; m < 32; m <<= 1) {
#pragma unroll
      for (int r = 0; r < 16; ++r) {
        y1p[r] += __shfl_xor(y1p[r], m);
        y2p[r] += __shfl_xor(y2p[r], m);
      }
    }
    if (l31 == 0) {
#pragma unroll
      for (int r = 0; r < 16; ++r) {
        const int row = (r & 3) + 8 * (r >> 2) + 4 * lhi;
        ly1[wv][row] = y1p[r];
        ly2[wv][row] = y2p[r];
      }
    }
    __syncthreads();  // (1) ly slots + new h + new c complete

    if (tid < TB_) {
      float s1 = b1v, s2 = b2v;
#pragma unroll
      for (int wq = 0; wq < 16; ++wq) { s1 += ly1[wq][tid]; s2 += ly2[wq][tid]; }
      float y1 = sigm(s1);
      float y2 = (s2 > 0.f) ? s2 : (__expf(s2) - 1.0f);
      out[(size_t)(b0 + tid) * KS_ + s] = y1;
      out[(size_t)B_ * KS_ + (size_t)(b0 + tid) * KS_ + s] = y2;
      x_lds[tid] = y1;
    }
    __syncthreads();  // (2) x visible before next step's gate loop
  }
}

extern "C" void kernel_launch(void* const* d_in, const int* in_sizes, int n_in,
                              void* d_out, int out_size, void* d_ws, size_t ws_size,
                              hipStream_t stream) {
  const float* initial = (const float*)d_in[0];
  const float* enc_h   = (const float*)d_in[1];
  const float* enc_c   = (const float*)d_in[2];
  const float* Wx      = (const float*)d_in[3];
  const float* Wu      = (const float*)d_in[4];
  const float* bias    = (const float*)d_in[5];
  const float* w1      = (const float*)d_in[6];
  const float* b1      = (const float*)d_in[7];
  const float* w2      = (const float*)d_in[8];
  const float* b2      = (const float*)d_in[9];
  u16* pk = (u16*)d_ws;  // 2 MB packed Wu (bf16, MFMA B-frag order)

  pack_wu_kernel<<<512, 256, 0, stream>>>(Wu, pk);
  lstm_kernel<<<256, 1024, 0, stream>>>(initial, enc_h, enc_c, Wx, bias, w1, b1,
                                        w2, b2, pk, (float*)d_out);
}

// Round 6
// 934.524 us; speedup vs baseline: 4.2692x; 3.3642x over previous
//
#include <hip/hip_runtime.h>

#define D_ 512
#define ND_ 2048   // 4*D
#define KS_ 24
#define TB_ 32
#define B_ 8192

typedef __attribute__((ext_vector_type(8))) short short8;
typedef __attribute__((ext_vector_type(16))) float f32x16;
typedef unsigned short u16;

// byte offset into swizzled h tile: row in [0,32), kb = byte offset along d (d*2)
#define SWZ(row, kb) (((row) * 1024) + ((kb) ^ (((row) & 15) << 4)))

__device__ __forceinline__ u16 f2bf(float f) {
  union { float f; unsigned int u; } v; v.f = f;
  unsigned int u = v.u;
  return (u16)((u + 0x7FFFu + ((u >> 16) & 1u)) >> 16);
}

__device__ __forceinline__ float sigm(float x) { return 1.0f / (1.0f + __expf(-x)); }
__device__ __forceinline__ float tanh_(float x) {
  float e = __expf(2.0f * x);
  return (e - 1.0f) / (e + 1.0f);
}

// async global->LDS, 16 B per lane; LDS dest is wave-uniform base + lane*16
__device__ __forceinline__ void glds16(const u16* g, void* l) {
  __builtin_amdgcn_global_load_lds(
      (const __attribute__((address_space(1))) unsigned int*)g,
      (__attribute__((address_space(3))) unsigned int*)l, 16, 0, 0);
}

// Pack Wu (512 x 2048 f32, row-major) into MFMA B-fragment order, bf16.
// Block (nt, ks): nt in [0,64) over 32-wide n-tiles, ks in [0,32) over K=16 slices.
// Within block: lane l, elem j  <->  B[k = ks*16 + 8*(l>>5) + j][n = nt*32 + (l&31)]
// Block storage: 64 lanes * 16B contiguous (1KB), block offset = (nt*32+ks)*1KB.
__global__ __launch_bounds__(256) void pack_wu_kernel(const float* __restrict__ Wu,
                                                      u16* __restrict__ pk) {
  int idx = blockIdx.x * 256 + threadIdx.x;  // 131072 total
  int lane = idx & 63;
  int blk  = idx >> 6;        // nt*32 + ks
  int ks   = blk & 31;
  int nt   = blk >> 5;
  int col  = nt * 32 + (lane & 31);
  int k0   = ks * 16 + (lane >> 5) * 8;
  u16 t[8];
#pragma unroll
  for (int j = 0; j < 8; ++j) t[j] = f2bf(Wu[(size_t)(k0 + j) * ND_ + col]);
  int4 w;
  w.x = t[0] | (t[1] << 16); w.y = t[2] | (t[3] << 16);
  w.z = t[4] | (t[5] << 16); w.w = t[6] | (t[7] << 16);
  *reinterpret_cast<int4*>(pk + (size_t)blk * 512 + lane * 8) = w;
}

// 256 blocks x 1024 threads (16 waves, 4 waves/SIMD -> 128 unified VGPR+AGPR cap).
// Wave wv owns 1 n-tile (32 d-cols) of each of the 4 gates; block = 32 rows.
// K-loop: Wu fragments staged via global_load_lds into a wave-private 4 KB LDS
// double buffer (zero VGPR cost), counted s_waitcnt vmcnt(2) — 32 KB/CU in
// flight covers L2 latency. acc 64 AGPR; c in 16 VGPR; h dbuf in LDS.
__global__ __launch_bounds__(1024, 4) void lstm_kernel(
    const float* __restrict__ initial, const float* __restrict__ enc_h,
    const float* __restrict__ enc_c, const float* __restrict__ Wx,
    const float* __restrict__ bias, const float* __restrict__ w1,
    const float* __restrict__ b1, const float* __restrict__ w2,
    const float* __restrict__ b2, const u16* __restrict__ wu,
    float* __restrict__ out) {
  __shared__ __align__(16) unsigned char hbuf[2][TB_ * 1024];   // 64 KB h dbuf
  __shared__ __align__(16) unsigned char wu_stage[16 * 4096];   // 64 KB stage
  __shared__ float x_lds[TB_];
  __shared__ float ly1[16][TB_];
  __shared__ float ly2[16][TB_];

  const int tid = threadIdx.x;
  const int wv  = tid >> 6;    // 0..15  == n-tile index within each gate region
  const int l   = tid & 63;
  const int l31 = l & 31;
  const int lhi = l >> 5;
  const int b0  = blockIdx.x * TB_;

  // ---- stage initial h (bf16, swizzled) into LDS: 1024 threads ----
  {
    int row = tid >> 5;   // 0..31
    int seg = tid & 31;   // 16 cols each
    const float* src = enc_h + (size_t)(b0 + row) * D_ + seg * 16;
#pragma unroll
    for (int jb = 0; jb < 2; ++jb) {
      u16 t[8];
#pragma unroll
      for (int j = 0; j < 8; ++j) t[j] = f2bf(src[jb * 8 + j]);
      int kb = seg * 32 + jb * 16;
      int4 w;
      w.x = t[0] | (t[1] << 16); w.y = t[2] | (t[3] << 16);
      w.z = t[4] | (t[5] << 16); w.w = t[6] | (t[7] << 16);
      *reinterpret_cast<int4*>(&hbuf[0][SWZ(row, kb)]) = w;
    }
  }
  if (tid < TB_) x_lds[tid] = initial[b0 + tid];

  // ---- per-lane step-invariant values ----
  const int col = wv * 32 + l31;     // d-column owned by this lane
  float wx[4], bb[4];
#pragma unroll
  for (int g = 0; g < 4; ++g) {
    wx[g] = Wx[g * D_ + col];
    bb[g] = bias[g * D_ + col];
  }
  const float w1v = w1[col], w2v = w2[col];
  const float b1v = b1[0], b2v = b2[0];

  // cell state in registers: creg[r] = c[row(r)][col]
  float creg[16];
#pragma unroll
  for (int r = 0; r < 16; ++r) {
    const int row = (r & 3) + 8 * (r >> 2) + 4 * lhi;
    creg[r] = enc_c[(size_t)(b0 + row) * D_ + col];
  }

  // 4 Wu fragment stream pointers (gate g, n-tile = g*16 + wv), advance 512 elem/ks
  const u16* p0 = wu + (size_t)(( 0 + wv) * 32) * 512 + (size_t)l * 8;
  const u16* p1 = wu + (size_t)((16 + wv) * 32) * 512 + (size_t)l * 8;
  const u16* p2 = wu + (size_t)((32 + wv) * 32) * 512 + (size_t)l * 8;
  const u16* p3 = wu + (size_t)((48 + wv) * 32) * 512 + (size_t)l * 8;

  unsigned char* stg = &wu_stage[wv * 4096];  // wave-private: [2 units][2 KB]
  const int lofs = l * 16;
  const int abase = lhi * 16;

  __syncthreads();

  for (int s = 0; s < KS_; ++s) {
    const unsigned char* hr = hbuf[s & 1];
    unsigned char* hw = hbuf[(s & 1) ^ 1];

    f32x16 acc0 = {}, acc1 = {}, acc2 = {}, acc3 = {};

    // prologue: issue unit 0 (gates 0,1 @ ks=0) into parity-0 buffer
    glds16(p0, stg);        p0 += 512;
    glds16(p1, stg + 1024); p1 += 512;

#pragma unroll 1
    for (int ks = 0; ks < 32; ++ks) {
      // issue unit 2ks+1 (gates 2,3 @ ks) into parity-1 buffer
      glds16(p2, stg + 2048); p2 += 512;
      glds16(p3, stg + 3072); p3 += 512;
      asm volatile("s_waitcnt vmcnt(2)" ::: "memory");  // unit 2ks complete
      short8 a  = *reinterpret_cast<const short8*>(&hr[SWZ(l31, ks * 32 + abase)]);
      short8 f0 = *reinterpret_cast<const short8*>(stg + lofs);
      short8 f1 = *reinterpret_cast<const short8*>(stg + 1024 + lofs);
      acc0 = __builtin_amdgcn_mfma_f32_32x32x16_bf16(a, f0, acc0, 0, 0, 0);
      acc1 = __builtin_amdgcn_mfma_f32_32x32x16_bf16(a, f1, acc1, 0, 0, 0);
      if (ks < 31) {
        // issue unit 2ks+2 (gates 0,1 @ ks+1) into parity-0 buffer
        glds16(p0, stg);        p0 += 512;
        glds16(p1, stg + 1024); p1 += 512;
        asm volatile("s_waitcnt vmcnt(2)" ::: "memory");  // unit 2ks+1 complete
      } else {
        asm volatile("s_waitcnt vmcnt(0)" ::: "memory");
      }
      short8 f2 = *reinterpret_cast<const short8*>(stg + 2048 + lofs);
      short8 f3 = *reinterpret_cast<const short8*>(stg + 3072 + lofs);
      acc2 = __builtin_amdgcn_mfma_f32_32x32x16_bf16(a, f2, acc2, 0, 0, 0);
      acc3 = __builtin_amdgcn_mfma_f32_32x32x16_bf16(a, f3, acc3, 0, 0, 0);
    }
    // reset stream pointers for next step (advanced 32*512 elems each)
    p0 -= 16384; p1 -= 16384; p2 -= 16384; p3 -= 16384;

    float y1p[16], y2p[16];
#pragma unroll
    for (int r = 0; r < 16; ++r) {
      const int row = (r & 3) + 8 * (r >> 2) + 4 * lhi;
      float xv = x_lds[row];
      float zi = acc0[r] + xv * wx[0] + bb[0];
      float zf = acc1[r] + xv * wx[1] + bb[1];
      float zg = acc2[r] + xv * wx[2] + bb[2];
      float zo = acc3[r] + xv * wx[3] + bb[3];
      float ig = sigm(zi);
      float fg = sigm(zf);
      float gg = tanh_(zg);
      float og = sigm(zo);
      float cn = fg * creg[r] + ig * gg;
      creg[r] = cn;
      float hn = og * tanh_(cn);
      *reinterpret_cast<u16*>(&hw[SWZ(row, col * 2)]) = f2bf(hn);
      y1p[r] = hn * w1v;
      y2p[r] = hn * w2v;
    }

    // reduce y partials across the 32 d-columns held by this half-wave
#pragma unroll
    for (int m = 1; m < 32; m <<= 1) {
#pragma unroll
      for (int r = 0; r < 16; ++r) {
        y1p[r] += __shfl_xor(y1p[r], m);
        y2p[r] += __shfl_xor(y2p[r], m);
      }
    }
    if (l31 == 0) {
#pragma unroll
      for (int r = 0; r < 16; ++r) {
        const int row = (r & 3) + 8 * (r >> 2) + 4 * lhi;
        ly1[wv][row] = y1p[r];
        ly2[wv][row] = y2p[r];
      }
    }
    __syncthreads();  // (1) ly slots + new h complete

    if (tid < TB_) {
      float s1 = b1v, s2 = b2v;
#pragma unroll
      for (int wq = 0; wq < 16; ++wq) { s1 += ly1[wq][tid]; s2 += ly2[wq][tid]; }
      float y1 = sigm(s1);
      float y2 = (s2 > 0.f) ? s2 : (__expf(s2) - 1.0f);
      out[(size_t)(b0 + tid) * KS_ + s] = y1;
      out[(size_t)B_ * KS_ + (size_t)(b0 + tid) * KS_ + s] = y2;
      x_lds[tid] = y1;
    }
    __syncthreads();  // (2) x visible before next step's gate loop
  }
}

extern "C" void kernel_launch(void* const* d_in, const int* in_sizes, int n_in,
                              void* d_out, int out_size, void* d_ws, size_t ws_size,
                              hipStream_t stream) {
  const float* initial = (const float*)d_in[0];
  const float* enc_h   = (const float*)d_in[1];
  const float* enc_c   = (const float*)d_in[2];
  const float* Wx      = (const float*)d_in[3];
  const float* Wu      = (const float*)d_in[4];
  const float* bias    = (const float*)d_in[5];
  const float* w1      = (const float*)d_in[6];
  const float* b1      = (const float*)d_in[7];
  const float* w2      = (const float*)d_in[8];
  const float* b2      = (const float*)d_in[9];
  u16* pk = (u16*)d_ws;  // 2 MB packed Wu (bf16, MFMA B-frag order)

  pack_wu_kernel<<<512, 256, 0, stream>>>(Wu, pk);
  lstm_kernel<<<256, 1024, 0, stream>>>(initial, enc_h, enc_c, Wx, bias, w1, b1,
                                        w2, b2, pk, (float*)d_out);
}

// Round 7
// 904.072 us; speedup vs baseline: 4.4130x; 1.0337x over previous
//
#include <hip/hip_runtime.h>

#define D_ 512
#define ND_ 2048   // 4*D
#define KS_ 24
#define TB_ 32
#define B_ 8192

typedef __attribute__((ext_vector_type(8))) short short8;
typedef __attribute__((ext_vector_type(16))) float f32x16;
typedef unsigned short u16;

// byte offset into swizzled h tile: row in [0,32), kb = byte offset along d (d*2)
#define SWZ(row, kb) (((row) * 1024) + ((kb) ^ (((row) & 15) << 4)))

__device__ __forceinline__ u16 f2bf(float f) {
  union { float f; unsigned int u; } v; v.f = f;
  unsigned int u = v.u;
  return (u16)((u + 0x7FFFu + ((u >> 16) & 1u)) >> 16);
}

__device__ __forceinline__ float sigm(float x) { return 1.0f / (1.0f + __expf(-x)); }
__device__ __forceinline__ float tanh_(float x) {
  float e = __expf(2.0f * x);
  return (e - 1.0f) / (e + 1.0f);
}

// async global->LDS, 16 B per lane; LDS dest is wave-uniform base + lane*16
__device__ __forceinline__ void glds16(const u16* g, void* l) {
  __builtin_amdgcn_global_load_lds(
      (const __attribute__((address_space(1))) unsigned int*)g,
      (__attribute__((address_space(3))) unsigned int*)l, 16, 0, 0);
}

// Pack Wu (512 x 2048 f32, row-major) into MFMA B-fragment order, bf16.
// Block (nt, ks): nt in [0,64) over 32-wide n-tiles, ks in [0,32) over K=16 slices.
// Within block: lane l, elem j  <->  B[k = ks*16 + 8*(l>>5) + j][n = nt*32 + (l&31)]
// Block storage: 64 lanes * 16B contiguous (1KB), block offset = (nt*32+ks)*1KB.
__global__ __launch_bounds__(256) void pack_wu_kernel(const float* __restrict__ Wu,
                                                      u16* __restrict__ pk) {
  int idx = blockIdx.x * 256 + threadIdx.x;  // 131072 total
  int lane = idx & 63;
  int blk  = idx >> 6;        // nt*32 + ks
  int ks   = blk & 31;
  int nt   = blk >> 5;
  int col  = nt * 32 + (lane & 31);
  int k0   = ks * 16 + (lane >> 5) * 8;
  u16 t[8];
#pragma unroll
  for (int j = 0; j < 8; ++j) t[j] = f2bf(Wu[(size_t)(k0 + j) * ND_ + col]);
  int4 w;
  w.x = t[0] | (t[1] << 16); w.y = t[2] | (t[3] << 16);
  w.z = t[4] | (t[5] << 16); w.w = t[6] | (t[7] << 16);
  *reinterpret_cast<int4*>(pk + (size_t)blk * 512 + lane * 8) = w;
}

// 256 blocks x 1024 threads (16 waves, 4 waves/SIMD -> 128 unified VGPR+AGPR).
// acc = 64 AGPR, so everything else must fit in 64 VGPR: creg 16 + params 12 +
// transients. Wu stream bases are wave-uniform (readfirstlane) -> SGPRs.
// y-reduction folded into the gate loop 4 rows at a time (8 live scalars).
// Wu staged via global_load_lds into wave-private 4 KB LDS dbuf, vmcnt(2).
__global__ __launch_bounds__(1024, 4) void lstm_kernel(
    const float* __restrict__ initial, const float* __restrict__ enc_h,
    const float* __restrict__ enc_c, const float* __restrict__ Wx,
    const float* __restrict__ bias, const float* __restrict__ w1,
    const float* __restrict__ b1, const float* __restrict__ w2,
    const float* __restrict__ b2, const u16* __restrict__ wu,
    float* __restrict__ out) {
  __shared__ __align__(16) unsigned char hbuf[2][TB_ * 1024];   // 64 KB h dbuf
  __shared__ __align__(16) unsigned char wu_stage[16 * 4096];   // 64 KB stage
  __shared__ float x_lds[TB_];
  __shared__ float ly1[16][TB_];
  __shared__ float ly2[16][TB_];

  const int tid = threadIdx.x;
  const int wv  = tid >> 6;
  const int wvu = __builtin_amdgcn_readfirstlane(wv);  // wave-uniform -> SGPR
  const int l   = tid & 63;
  const int l31 = l & 31;
  const int lhi = l >> 5;
  const int b0  = blockIdx.x * TB_;

  // ---- stage initial h (bf16, swizzled) into LDS: 1024 threads ----
  {
    int row = tid >> 5;   // 0..31
    int seg = tid & 31;   // 16 cols each
    const float* src = enc_h + (size_t)(b0 + row) * D_ + seg * 16;
#pragma unroll
    for (int jb = 0; jb < 2; ++jb) {
      u16 t[8];
#pragma unroll
      for (int j = 0; j < 8; ++j) t[j] = f2bf(src[jb * 8 + j]);
      int kb = seg * 32 + jb * 16;
      int4 w;
      w.x = t[0] | (t[1] << 16); w.y = t[2] | (t[3] << 16);
      w.z = t[4] | (t[5] << 16); w.w = t[6] | (t[7] << 16);
      *reinterpret_cast<int4*>(&hbuf[0][SWZ(row, kb)]) = w;
    }
  }
  if (tid < TB_) x_lds[tid] = initial[b0 + tid];

  // ---- per-lane step-invariant values ----
  const int col = wvu * 32 + l31;    // d-column owned by this lane
  float wx[4], bb[4];
#pragma unroll
  for (int g = 0; g < 4; ++g) {
    wx[g] = Wx[g * D_ + col];
    bb[g] = bias[g * D_ + col];
  }
  const float w1v = w1[col], w2v = w2[col];
  const float b1v = b1[0], b2v = b2[0];

  // cell state in registers: creg[r] = c[row(r)][col]
  float creg[16];
#pragma unroll
  for (int r = 0; r < 16; ++r) {
    const int row = (r & 3) + 8 * (r >> 2) + 4 * lhi;
    creg[r] = enc_c[(size_t)(b0 + row) * D_ + col];
  }

  // wave-uniform Wu stream bases (gate g -> n-tile g*16 + wvu); SGPR-resident
  const u16* wb0 = wu + (size_t)(( 0 + wvu) * 32) * 512;
  const u16* wb1 = wu + (size_t)((16 + wvu) * 32) * 512;
  const u16* wb2 = wu + (size_t)((32 + wvu) * 32) * 512;
  const u16* wb3 = wu + (size_t)((48 + wvu) * 32) * 512;
  const size_t lofs8 = (size_t)l * 8;   // per-lane element offset into each 1 KB unit

  unsigned char* stg = &wu_stage[wvu * 4096];  // wave-private: [2 units][2 KB]
  const int lofs = l * 16;
  const int abase = lhi * 16;

  __syncthreads();

  for (int s = 0; s < KS_; ++s) {
    const unsigned char* hr = hbuf[s & 1];
    unsigned char* hw = hbuf[(s & 1) ^ 1];

    f32x16 acc0 = {}, acc1 = {}, acc2 = {}, acc3 = {};

    // prologue: issue unit 0 (gates 0,1 @ ks=0) into parity-0 buffer
    glds16(wb0 + lofs8, stg);
    glds16(wb1 + lofs8, stg + 1024);

#pragma unroll 1
    for (int ks = 0; ks < 32; ++ks) {
      const size_t o = (size_t)ks * 512 + lofs8;
      // issue unit 2ks+1 (gates 2,3 @ ks) into parity-1 buffer
      glds16(wb2 + o, stg + 2048);
      glds16(wb3 + o, stg + 3072);
      asm volatile("s_waitcnt vmcnt(2)" ::: "memory");  // unit 2ks complete
      short8 a  = *reinterpret_cast<const short8*>(&hr[SWZ(l31, ks * 32 + abase)]);
      short8 f0 = *reinterpret_cast<const short8*>(stg + lofs);
      short8 f1 = *reinterpret_cast<const short8*>(stg + 1024 + lofs);
      acc0 = __builtin_amdgcn_mfma_f32_32x32x16_bf16(a, f0, acc0, 0, 0, 0);
      acc1 = __builtin_amdgcn_mfma_f32_32x32x16_bf16(a, f1, acc1, 0, 0, 0);
      if (ks < 31) {
        // issue unit 2ks+2 (gates 0,1 @ ks+1) into parity-0 buffer
        const size_t o2 = (size_t)(ks + 1) * 512 + lofs8;
        glds16(wb0 + o2, stg);
        glds16(wb1 + o2, stg + 1024);
        asm volatile("s_waitcnt vmcnt(2)" ::: "memory");  // unit 2ks+1 complete
      } else {
        asm volatile("s_waitcnt vmcnt(0)" ::: "memory");
      }
      short8 f2 = *reinterpret_cast<const short8*>(stg + 2048 + lofs);
      short8 f3 = *reinterpret_cast<const short8*>(stg + 3072 + lofs);
      acc2 = __builtin_amdgcn_mfma_f32_32x32x16_bf16(a, f2, acc2, 0, 0, 0);
      acc3 = __builtin_amdgcn_mfma_f32_32x32x16_bf16(a, f3, acc3, 0, 0, 0);
    }

    // gate math + y-reduction, 4 rows per batch (8 live y scalars, no arrays)
#pragma unroll
    for (int rb = 0; rb < 16; rb += 4) {
      float y1t[4], y2t[4];
#pragma unroll
      for (int q = 0; q < 4; ++q) {
        const int r = rb + q;
        const int row = (r & 3) + 8 * (r >> 2) + 4 * lhi;
        float xv = x_lds[row];
        float zi = acc0[r] + xv * wx[0] + bb[0];
        float zf = acc1[r] + xv * wx[1] + bb[1];
        float zg = acc2[r] + xv * wx[2] + bb[2];
        float zo = acc3[r] + xv * wx[3] + bb[3];
        float ig = sigm(zi);
        float fg = sigm(zf);
        float gg = tanh_(zg);
        float og = sigm(zo);
        float cn = fg * creg[r] + ig * gg;
        creg[r] = cn;
        float hn = og * tanh_(cn);
        *reinterpret_cast<u16*>(&hw[SWZ(row, col * 2)]) = f2bf(hn);
        y1t[q] = hn * w1v;
        y2t[q] = hn * w2v;
      }
#pragma unroll
      for (int m = 1; m < 32; m <<= 1) {
#pragma unroll
        for (int q = 0; q < 4; ++q) {
          y1t[q] += __shfl_xor(y1t[q], m);
          y2t[q] += __shfl_xor(y2t[q], m);
        }
      }
      if (l31 == 0) {
#pragma unroll
        for (int q = 0; q < 4; ++q) {
          const int r = rb + q;
          const int row = (r & 3) + 8 * (r >> 2) + 4 * lhi;
          ly1[wvu][row] = y1t[q];
          ly2[wvu][row] = y2t[q];
        }
      }
    }
    __syncthreads();  // (1) ly slots + new h complete

    if (tid < TB_) {
      float s1 = b1v, s2 = b2v;
#pragma unroll
      for (int wq = 0; wq < 16; ++wq) { s1 += ly1[wq][tid]; s2 += ly2[wq][tid]; }
      float y1 = sigm(s1);
      float y2 = (s2 > 0.f) ? s2 : (__expf(s2) - 1.0f);
      out[(size_t)(b0 + tid) * KS_ + s] = y1;
      out[(size_t)B_ * KS_ + (size_t)(b0 + tid) * KS_ + s] = y2;
      x_lds[tid] = y1;
    }
    __syncthreads();  // (2) x visible before next step's gate loop
  }
}

extern "C" void kernel_launch(void* const* d_in, const int* in_sizes, int n_in,
                              void* d_out, int out_size, void* d_ws, size_t ws_size,
                              hipStream_t stream) {
  const float* initial = (const float*)d_in[0];
  const float* enc_h   = (const float*)d_in[1];
  const float* enc_c   = (const float*)d_in[2];
  const float* Wx      = (const float*)d_in[3];
  const float* Wu      = (const float*)d_in[4];
  const float* bias    = (const float*)d_in[5];
  const float* w1      = (const float*)d_in[6];
  const float* b1      = (const float*)d_in[7];
  const float* w2      = (const float*)d_in[8];
  const float* b2      = (const float*)d_in[9];
  u16* pk = (u16*)d_ws;  // 2 MB packed Wu (bf16, MFMA B-frag order)

  pack_wu_kernel<<<512, 256, 0, stream>>>(Wu, pk);
  lstm_kernel<<<256, 1024, 0, stream>>>(initial, enc_h, enc_c, Wx, bias, w1, b1,
                                        w2, b2, pk, (float*)d_out);
}

// Round 8
// 834.781 us; speedup vs baseline: 4.7793x; 1.0830x over previous
//
#include <hip/hip_runtime.h>

#define D_ 512
#define ND_ 2048   // 4*D
#define KS_ 24
#define TB_ 32
#define B_ 8192
#define NU_ 33     // 32 K-units of Wu + 1 ext unit [Wx; b]

typedef __attribute__((ext_vector_type(8))) short short8;
typedef __attribute__((ext_vector_type(16))) float f32x16;
typedef unsigned short u16;

// byte offset into swizzled h tile: row in [0,32), kb = byte offset along d (d*2)
#define SWZ(row, kb) (((row) * 1024) + ((kb) ^ (((row) & 15) << 4)))

__device__ __forceinline__ u16 f2bf(float f) {
  union { float f; unsigned int u; } v; v.f = f;
  unsigned int u = v.u;
  return (u16)((u + 0x7FFFu + ((u >> 16) & 1u)) >> 16);
}

__device__ __forceinline__ float sigm(float x) { return 1.0f / (1.0f + __expf(-x)); }
__device__ __forceinline__ float tanh_(float x) {
  float e = __expf(2.0f * x);
  return (e - 1.0f) / (e + 1.0f);
}

// async global->LDS, 16 B per lane; LDS dest is wave-uniform base + lane*16
__device__ __forceinline__ void glds16(const u16* g, void* l) {
  __builtin_amdgcn_global_load_lds(
      (const __attribute__((address_space(1))) unsigned int*)g,
      (__attribute__((address_space(3))) unsigned int*)l, 16, 0, 0);
}

// Pack [Wu; Wx; b] into MFMA B-fragment order, bf16.
// Stream (nt): 33 units of 1 KB. Units 0..31: Wu K-slices
//   lane l, elem j <-> Wu[k = un*16 + 8*(l>>5) + j][n = nt*32 + (l&31)]
// Unit 32 (ext): k=0 -> Wx[n], k=1 -> b[n], k>=2 -> 0  (z = x*Wx + h@Wu + b
// becomes [h, x, 1] @ [Wu; Wx; b] -- bias and input folded into the MFMA).
__global__ __launch_bounds__(256) void pack_wu_kernel(const float* __restrict__ Wu,
                                                      const float* __restrict__ Wx,
                                                      const float* __restrict__ b,
                                                      u16* __restrict__ pk) {
  int idx = blockIdx.x * 256 + threadIdx.x;  // 2112 units * 64 lanes = 135168
  int lane = idx & 63;
  int unit = idx >> 6;        // 0..2111 = nt*33 + un
  if (unit >= 64 * NU_) return;
  int nt = unit / NU_;
  int un = unit - nt * NU_;
  int col = nt * 32 + (lane & 31);
  u16 t[8] = {0, 0, 0, 0, 0, 0, 0, 0};
  if (un < 32) {
    int k0 = un * 16 + (lane >> 5) * 8;
#pragma unroll
    for (int j = 0; j < 8; ++j) t[j] = f2bf(Wu[(size_t)(k0 + j) * ND_ + col]);
  } else if ((lane >> 5) == 0) {
    t[0] = f2bf(Wx[col]);
    t[1] = f2bf(b[col]);
  }
  int4 w;
  w.x = t[0] | (t[1] << 16); w.y = t[2] | (t[3] << 16);
  w.z = t[4] | (t[5] << 16); w.w = t[6] | (t[7] << 16);
  *reinterpret_cast<int4*>(pk + (size_t)unit * 512 + lane * 8) = w;
}

// 256 blocks x 1024 threads (16 waves, 4 waves/SIMD -> 128 unified VGPR+AGPR).
// acc = 64 AGPR; everything else fits in 64 VGPR now that x/b/bias are folded
// into the MFMA (no wx[]/bb[] arrays, no xv in the gate loop).
// Wu staged via global_load_lds into wave-private 4 KB LDS dbuf, vmcnt(2).
__global__ __launch_bounds__(1024, 4) void lstm_kernel(
    const float* __restrict__ initial, const float* __restrict__ enc_h,
    const float* __restrict__ enc_c,
    const float* __restrict__ w1, const float* __restrict__ b1,
    const float* __restrict__ w2, const float* __restrict__ b2,
    const u16* __restrict__ wu, float* __restrict__ out) {
  __shared__ __align__(16) unsigned char hbuf[2][TB_ * 1024];   // 64 KB h dbuf
  __shared__ __align__(16) unsigned char wu_stage[16 * 4096];   // 64 KB stage
  __shared__ float x_lds[TB_];
  __shared__ float ly1[16][TB_];
  __shared__ float ly2[16][TB_];

  const int tid = threadIdx.x;
  const int wv  = tid >> 6;
  const int wvu = __builtin_amdgcn_readfirstlane(wv);  // wave-uniform -> SGPR
  const int l   = tid & 63;
  const int l31 = l & 31;
  const int lhi = l >> 5;
  const int b0  = blockIdx.x * TB_;

  // ---- stage initial h (bf16, swizzled) into LDS: 1024 threads ----
  {
    int row = tid >> 5;   // 0..31
    int seg = tid & 31;   // 16 cols each
    const float* src = enc_h + (size_t)(b0 + row) * D_ + seg * 16;
#pragma unroll
    for (int jb = 0; jb < 2; ++jb) {
      u16 t[8];
#pragma unroll
      for (int j = 0; j < 8; ++j) t[j] = f2bf(src[jb * 8 + j]);
      int kb = seg * 32 + jb * 16;
      int4 w;
      w.x = t[0] | (t[1] << 16); w.y = t[2] | (t[3] << 16);
      w.z = t[4] | (t[5] << 16); w.w = t[6] | (t[7] << 16);
      *reinterpret_cast<int4*>(&hbuf[0][SWZ(row, kb)]) = w;
    }
  }
  if (tid < TB_) x_lds[tid] = initial[b0 + tid];

  // ---- per-lane step-invariant values ----
  const int col = wvu * 32 + l31;    // d-column owned by this lane
  const float w1v = w1[col], w2v = w2[col];
  const float b1v = b1[0], b2v = b2[0];

  // cell state in registers: creg[r] = c[row(r)][col]
  float creg[16];
#pragma unroll
  for (int r = 0; r < 16; ++r) {
    const int row = (r & 3) + 8 * (r >> 2) + 4 * lhi;
    creg[r] = enc_c[(size_t)(b0 + row) * D_ + col];
  }

  // wave-uniform Wu stream bases (gate g -> n-tile g*16 + wvu); SGPR-resident
  const u16* wb0 = wu + (size_t)(( 0 + wvu) * NU_) * 512;
  const u16* wb1 = wu + (size_t)((16 + wvu) * NU_) * 512;
  const u16* wb2 = wu + (size_t)((32 + wvu) * NU_) * 512;
  const u16* wb3 = wu + (size_t)((48 + wvu) * NU_) * 512;
  const size_t lofs8 = (size_t)l * 8;   // per-lane element offset into each 1 KB unit

  unsigned char* stg = &wu_stage[wvu * 4096];  // wave-private: [2 units][2 KB]
  const int lofs = l * 16;
  const int abase = lhi * 16;

  __syncthreads();

  for (int s = 0; s < KS_; ++s) {
    const unsigned char* hr = hbuf[s & 1];
    unsigned char* hw = hbuf[(s & 1) ^ 1];

    f32x16 acc0 = {}, acc1 = {}, acc2 = {}, acc3 = {};

    // prologue: issue unit 0 (gates 0,1 @ ks=0) into parity-0 buffer
    glds16(wb0 + lofs8, stg);
    glds16(wb1 + lofs8, stg + 1024);

#pragma unroll 1
    for (int ks = 0; ks <= 32; ++ks) {
      const size_t o = (size_t)ks * 512 + lofs8;
      // issue unit pair (gates 2,3 @ ks) into parity-1 buffer
      glds16(wb2 + o, stg + 2048);
      glds16(wb3 + o, stg + 3072);
      asm volatile("s_waitcnt vmcnt(2)" ::: "memory");  // gates 0,1 @ ks complete
      short8 a;
      if (ks < 32) {
        a = *reinterpret_cast<const short8*>(&hr[SWZ(l31, ks * 32 + abase)]);
      } else {
        // ext slice: h_ext = [x, 1, 0...] rows (only k=0,1 of lower half)
        short8 z8 = {};
        a = z8;
        if (lhi == 0) {
          a[0] = (short)f2bf(x_lds[l31]);
          a[1] = (short)0x3F80;  // 1.0 bf16
        }
      }
      short8 f0 = *reinterpret_cast<const short8*>(stg + lofs);
      short8 f1 = *reinterpret_cast<const short8*>(stg + 1024 + lofs);
      acc0 = __builtin_amdgcn_mfma_f32_32x32x16_bf16(a, f0, acc0, 0, 0, 0);
      acc1 = __builtin_amdgcn_mfma_f32_32x32x16_bf16(a, f1, acc1, 0, 0, 0);
      if (ks < 32) {
        // issue gates 0,1 @ ks+1 into parity-0 buffer
        const size_t o2 = (size_t)(ks + 1) * 512 + lofs8;
        glds16(wb0 + o2, stg);
        glds16(wb1 + o2, stg + 1024);
        asm volatile("s_waitcnt vmcnt(2)" ::: "memory");  // gates 2,3 @ ks complete
      } else {
        asm volatile("s_waitcnt vmcnt(0)" ::: "memory");
      }
      short8 f2 = *reinterpret_cast<const short8*>(stg + 2048 + lofs);
      short8 f3 = *reinterpret_cast<const short8*>(stg + 3072 + lofs);
      acc2 = __builtin_amdgcn_mfma_f32_32x32x16_bf16(a, f2, acc2, 0, 0, 0);
      acc3 = __builtin_amdgcn_mfma_f32_32x32x16_bf16(a, f3, acc3, 0, 0, 0);
    }

    // gate math + y-reduction, 4 rows per batch (8 live y scalars, no arrays)
#pragma unroll
    for (int rb = 0; rb < 16; rb += 4) {
      float y1t[4], y2t[4];
#pragma unroll
      for (int q = 0; q < 4; ++q) {
        const int r = rb + q;
        const int row = (r & 3) + 8 * (r >> 2) + 4 * lhi;
        float ig = sigm(acc0[r]);
        float fg = sigm(acc1[r]);
        float gg = tanh_(acc2[r]);
        float og = sigm(acc3[r]);
        float cn = fg * creg[r] + ig * gg;
        creg[r] = cn;
        float hn = og * tanh_(cn);
        *reinterpret_cast<u16*>(&hw[SWZ(row, col * 2)]) = f2bf(hn);
        y1t[q] = hn * w1v;
        y2t[q] = hn * w2v;
      }
#pragma unroll
      for (int m = 1; m < 32; m <<= 1) {
#pragma unroll
        for (int q = 0; q < 4; ++q) {
          y1t[q] += __shfl_xor(y1t[q], m);
          y2t[q] += __shfl_xor(y2t[q], m);
        }
      }
      if (l31 == 0) {
#pragma unroll
        for (int q = 0; q < 4; ++q) {
          const int r = rb + q;
          const int row = (r & 3) + 8 * (r >> 2) + 4 * lhi;
          ly1[wvu][row] = y1t[q];
          ly2[wvu][row] = y2t[q];
        }
      }
    }
    __syncthreads();  // (1) ly slots + new h complete

    if (tid < TB_) {
      float s1 = b1v, s2 = b2v;
#pragma unroll
      for (int wq = 0; wq < 16; ++wq) { s1 += ly1[wq][tid]; s2 += ly2[wq][tid]; }
      float y1 = sigm(s1);
      float y2 = (s2 > 0.f) ? s2 : (__expf(s2) - 1.0f);
      out[(size_t)(b0 + tid) * KS_ + s] = y1;
      out[(size_t)B_ * KS_ + (size_t)(b0 + tid) * KS_ + s] = y2;
      x_lds[tid] = y1;
    }
    __syncthreads();  // (2) x + h visible before next step
  }
}

extern "C" void kernel_launch(void* const* d_in, const int* in_sizes, int n_in,
                              void* d_out, int out_size, void* d_ws, size_t ws_size,
                              hipStream_t stream) {
  const float* initial = (const float*)d_in[0];
  const float* enc_h   = (const float*)d_in[1];
  const float* enc_c   = (const float*)d_in[2];
  const float* Wx      = (const float*)d_in[3];
  const float* Wu      = (const float*)d_in[4];
  const float* bias    = (const float*)d_in[5];
  const float* w1      = (const float*)d_in[6];
  const float* b1      = (const float*)d_in[7];
  const float* w2      = (const float*)d_in[8];
  const float* b2      = (const float*)d_in[9];
  u16* pk = (u16*)d_ws;  // 2.06 MB packed [Wu; Wx; b] (bf16, MFMA B-frag order)

  pack_wu_kernel<<<528, 256, 0, stream>>>(Wu, Wx, bias, pk);
  lstm_kernel<<<256, 1024, 0, stream>>>(initial, enc_h, enc_c, w1, b1,
                                        w2, b2, pk, (float*)d_out);
}